// Round 1
// baseline (1363.623 us; speedup 1.0000x reference)
//
#include <hip/hip_runtime.h>

#define EPS_BN 1e-5f

// ---------------- workspace layout (float-unit offsets) ----------------
#define O_SRCD   0u
#define O_DSTD   17024u
#define O_COUNTS 34048u
#define O_OFFS   35072u
#define O_CURS   36096u
#define O_EIDX   37120u
#define O_PW1    54144u                    // [32][640]  (Wl1T|Wr1T|WpT)
#define O_PW2    74624u                    // [256][256] (Wl2T|Wr2T)
#define O_LW     140160u                   // [2][128k][128j][8]
#define O_BCOMB  402304u                   // [2][128j][4]
#define O_ABF    403328u                   // A1(256)|B1(256)|A2(128)|B2(128)
#define O_HWT    404352u                   // Ws1T(832)|Ws2T(2048)|Wh1T(10240)
#define O_BIG0   417536u                   // XL1  | later XL2,XR2
#define O_BIG1   (O_BIG0 + 16384000u)      // XR1  | later LO
#define O_BIG2   (O_BIG1 + 16384000u)      // H1
#define O_BIG3   (O_BIG2 + 16384000u)      // XP
#define O_BIG4   (O_BIG3 + 8192000u)       // Hres

__device__ __forceinline__ float rsum32(float p) {
  p += __shfl_xor(p, 1);  p += __shfl_xor(p, 2);  p += __shfl_xor(p, 4);
  p += __shfl_xor(p, 8);  p += __shfl_xor(p, 16); return p;
}
__device__ __forceinline__ float rsum64(float p) {
  p = rsum32(p); p += __shfl_xor(p, 32); return p;
}
__device__ __forceinline__ float lrelu(float x) { return x > 0.f ? x : 0.2f * x; }
__device__ __forceinline__ float eluf(float x)  { return x > 0.f ? x : expm1f(x); }
__device__ __forceinline__ float geluf(float x) { return 0.5f * x * (1.f + erff(x * 0.70710678118654752f)); }

// ---------------- prep kernels ----------------
__global__ void prep_edges(const int* __restrict__ ei, int* __restrict__ srcD,
                           int* __restrict__ dstD, int* __restrict__ counts) {
  int i = blockIdx.x * 256 + threadIdx.x;
  if (i < 1024) counts[i] = 0;
  if (i < 17000) {
    int s = (i < 16000) ? ei[i] : (i - 16000);
    int d = (i < 16000) ? ei[16000 + i] : (i - 16000);
    srcD[i] = s; dstD[i] = d;
  }
}
__global__ void hist_kernel(const int* __restrict__ dstD, int* __restrict__ counts) {
  int i = blockIdx.x * 256 + threadIdx.x;
  if (i < 17000) atomicAdd(&counts[dstD[i]], 1);
}
__global__ void scan_kernel(const int* __restrict__ counts, int* __restrict__ offs,
                            int* __restrict__ curs) {
  __shared__ int sh[1024];
  int i = threadIdx.x;
  int v = (i < 1000) ? counts[i] : 0;
  sh[i] = v;
  __syncthreads();
  for (int d = 1; d < 1024; d <<= 1) {
    int t = (i >= d) ? sh[i - d] : 0;
    __syncthreads();
    sh[i] += t;
    __syncthreads();
  }
  if (i < 1000) { offs[i + 1] = sh[i]; curs[i] = sh[i] - v; }
  if (i == 0) offs[0] = 0;
}
__global__ void fill_kernel(const int* __restrict__ dstD, int* __restrict__ curs,
                            int* __restrict__ eidx) {
  int i = blockIdx.x * 256 + threadIdx.x;
  if (i < 17000) { int p = atomicAdd(&curs[dstD[i]], 1); eidx[p] = i; }
}

__global__ void pack_kernel(
    const float* __restrict__ Wl1, const float* __restrict__ Wr1, const float* __restrict__ Wp,
    const float* __restrict__ Wl2, const float* __restrict__ Wr2,
    const float* __restrict__ Wih0, const float* __restrict__ Whh0,
    const float* __restrict__ bih0, const float* __restrict__ bhh0,
    const float* __restrict__ Wih1, const float* __restrict__ Whh1,
    const float* __restrict__ bih1, const float* __restrict__ bhh1,
    const float* __restrict__ g1, const float* __restrict__ be1, const float* __restrict__ m1,
    const float* __restrict__ v1, const float* __restrict__ bg1,
    const float* __restrict__ g2, const float* __restrict__ be2, const float* __restrict__ m2,
    const float* __restrict__ v2, const float* __restrict__ bg2,
    const float* __restrict__ Ws1, const float* __restrict__ Ws2, const float* __restrict__ Wh1,
    float* __restrict__ PW1, float* __restrict__ PW2, float* __restrict__ LW,
    float* __restrict__ BC, float* __restrict__ ABF, float* __restrict__ HWT)
{
  int i = blockIdx.x * 256 + threadIdx.x;
  if (i < 262144) {  // LSTM packed weights
    int u = i & 7, j = (i >> 3) & 127, k = (i >> 10) & 127, L = i >> 17;
    const float* Wih = L ? Wih1 : Wih0;
    const float* Whh = L ? Whh1 : Whh0;
    LW[i] = (u < 4) ? Wih[(u * 128 + j) * 128 + k] : Whh[((u - 4) * 128 + j) * 128 + k];
  }
  if (i < 65536) { int c = i & 255, k = i >> 8;
    PW2[i] = (c < 128) ? Wl2[c * 256 + k] : Wr2[(c - 128) * 256 + k]; }
  if (i < 20480) { int g = i % 640, k = i / 640;
    PW1[i] = (g < 256) ? Wl1[g * 32 + k] : (g < 512) ? Wr1[(g - 256) * 32 + k]
                                                     : Wp[(g - 512) * 32 + k]; }
  if (i < 1024) { int u = i & 3, j = (i >> 2) & 127, L = i >> 9;
    BC[i] = (L ? bih1 : bih0)[u * 128 + j] + (L ? bhh1 : bhh0)[u * 128 + j]; }
  if (i < 768) {
    if (i < 256) ABF[i] = g1[i] * rsqrtf(v1[i] + EPS_BN);
    else if (i < 512) { int c = i - 256; float a = g1[c] * rsqrtf(v1[c] + EPS_BN);
      ABF[i] = (bg1[c] - m1[c]) * a + be1[c]; }
    else if (i < 640) { int c = i - 512; ABF[i] = g2[c] * rsqrtf(v2[c] + EPS_BN); }
    else { int c = i - 640; float a = g2[c] * rsqrtf(v2[c] + EPS_BN);
      ABF[i] = (bg2[c] - m2[c]) * a + be2[c]; }
  }
  if (i < 13120) {
    if (i < 832) { int l = i & 63, c = i >> 6; HWT[i] = Ws1[l * 13 + c]; }
    else if (i < 2880) { int k = i - 832; int l = k & 31, jj = k >> 5; HWT[i] = Ws2[l * 64 + jj]; }
    else { int k = i - 2880; int l = k & 63, r = k >> 6; HWT[i] = Wh1[l * 160 + r]; }
  }
}

// ---------------- projection 1: x -> xl1(256) | xr1(256) | xp(128) ----------------
__global__ __launch_bounds__(320)
void proj1_kernel(const float* __restrict__ X, const float* __restrict__ PW1,
                  const float* __restrict__ bp,
                  float* __restrict__ XL1, float* __restrict__ XR1, float* __restrict__ XP)
{
  __shared__ float xs[32][16];
  const int tid = threadIdx.x;
  const int r0 = blockIdx.x * 16;
  for (int el = tid; el < 512; el += 320) {
    int r = el >> 5, k = el & 31;
    xs[k][r] = X[(size_t)(r0 + r) * 32 + k];
  }
  __syncthreads();
  const int gA = tid, gB = tid + 320;
  float accA[16], accB[16];
  const float iB = (gB >= 512) ? bp[gB - 512] : 0.f;
  #pragma unroll
  for (int r = 0; r < 16; ++r) { accA[r] = 0.f; accB[r] = iB; }
  for (int k = 0; k < 32; ++k) {
    float wA = PW1[k * 640 + gA], wB = PW1[k * 640 + gB];
    float xv[16];
    #pragma unroll
    for (int q = 0; q < 4; ++q)
      *reinterpret_cast<float4*>(&xv[q * 4]) = *reinterpret_cast<const float4*>(&xs[k][q * 4]);
    #pragma unroll
    for (int r = 0; r < 16; ++r) {
      accA[r] = fmaf(wA, xv[r], accA[r]);
      accB[r] = fmaf(wB, xv[r], accB[r]);
    }
  }
  for (int r = 0; r < 16; ++r) {
    size_t row = r0 + r;
    if (gA < 256) XL1[row * 256 + gA] = accA[r];
    else          XR1[row * 256 + (gA - 256)] = accA[r];
    if (gB < 512) XR1[row * 256 + (gB - 256)] = accB[r];
    else          XP[row * 128 + (gB - 512)] = accB[r];
  }
}

// ---------------- GAT layer 1 fused (2 heads, d=128) ----------------
__global__ __launch_bounds__(256)
void gat1_kernel(const float* __restrict__ XL, const float* __restrict__ XR,
                 const int* __restrict__ srcD, const int* __restrict__ eidx,
                 const int* __restrict__ offs, const float* __restrict__ a1,
                 const float* __restrict__ ABF, float* __restrict__ H1)
{
  const int lane = threadIdx.x & 63;
  const int wv = threadIdx.x >> 6;
  const int n = blockIdx.x * 4 + wv;
  const int b = blockIdx.y;
  const int half = lane >> 5;
  __shared__ float lsh[4][128];
  const int beg = offs[n];
  const int deg = offs[n + 1] - beg;
  const float4 a4 = reinterpret_cast<const float4*>(a1)[lane];
  const float4 xr4 = reinterpret_cast<const float4*>(XR + (size_t)(b * 1000 + n) * 256)[lane];
  float m = -INFINITY, ssum = 0.f;
  for (int i = 0; i < deg; ++i) {
    const int e = eidx[beg + i];
    const int s = srcD[e];
    const float4 xl4 = reinterpret_cast<const float4*>(XL + (size_t)(b * 1000 + s) * 256)[lane];
    float p = lrelu(xl4.x + xr4.x) * a4.x + lrelu(xl4.y + xr4.y) * a4.y
            + lrelu(xl4.z + xr4.z) * a4.z + lrelu(xl4.w + xr4.w) * a4.w;
    p = rsum32(p);
    if (i < 64 && (lane & 31) == 0) lsh[wv][2 * i + half] = p;
    float mn = fmaxf(m, p);
    ssum = ssum * __expf(m - mn) + __expf(p - mn);
    m = mn;
  }
  const float inv = 1.f / ssum;
  __builtin_amdgcn_wave_barrier();
  float4 acc = make_float4(0.f, 0.f, 0.f, 0.f);
  for (int i = 0; i < deg; ++i) {
    const int e = eidx[beg + i];
    const int s = srcD[e];
    const float4 xl4 = reinterpret_cast<const float4*>(XL + (size_t)(b * 1000 + s) * 256)[lane];
    float lg;
    if (i < 64) lg = lsh[wv][2 * i + half];
    else {
      float p = lrelu(xl4.x + xr4.x) * a4.x + lrelu(xl4.y + xr4.y) * a4.y
              + lrelu(xl4.z + xr4.z) * a4.z + lrelu(xl4.w + xr4.w) * a4.w;
      lg = rsum32(p);
    }
    const float al = __expf(lg - m) * inv;
    acc.x = fmaf(al, xl4.x, acc.x);
    acc.y = fmaf(al, xl4.y, acc.y);
    acc.z = fmaf(al, xl4.z, acc.z);
    acc.w = fmaf(al, xl4.w, acc.w);
  }
  const float4 A4 = reinterpret_cast<const float4*>(ABF)[lane];
  const float4 B4 = reinterpret_cast<const float4*>(ABF + 256)[lane];
  float4 o;
  o.x = eluf(fmaf(acc.x, A4.x, B4.x));
  o.y = eluf(fmaf(acc.y, A4.y, B4.y));
  o.z = eluf(fmaf(acc.z, A4.z, B4.z));
  o.w = eluf(fmaf(acc.w, A4.w, B4.w));
  reinterpret_cast<float4*>(H1 + (size_t)(b * 1000 + n) * 256)[lane] = o;
}

// ---------------- projection 2: h1(256) -> xl2(128)|xr2(128) ----------------
__global__ __launch_bounds__(128)
void proj2_kernel(const float* __restrict__ H1, const float* __restrict__ PW2,
                  float* __restrict__ XL2, float* __restrict__ XR2)
{
  __shared__ float xs[256][36];
  const int tid = threadIdx.x;           // 0..127
  const int r0 = blockIdx.x * 32;
  for (int el = tid; el < 8192; el += 128) {
    int k = el & 255, r = el >> 8;
    xs[k][r] = H1[(size_t)(r0 + r) * 256 + k];
  }
  __syncthreads();
  float acc0[32], acc1[32];
  #pragma unroll
  for (int r = 0; r < 32; ++r) { acc0[r] = 0.f; acc1[r] = 0.f; }
  for (int k = 0; k < 256; ++k) {
    float w0 = PW2[k * 256 + tid], w1 = PW2[k * 256 + tid + 128];
    float xv[32];
    #pragma unroll
    for (int q = 0; q < 8; ++q)
      *reinterpret_cast<float4*>(&xv[q * 4]) = *reinterpret_cast<const float4*>(&xs[k][q * 4]);
    #pragma unroll
    for (int r = 0; r < 32; ++r) {
      acc0[r] = fmaf(w0, xv[r], acc0[r]);
      acc1[r] = fmaf(w1, xv[r], acc1[r]);
    }
  }
  for (int r = 0; r < 32; ++r) {
    XL2[(size_t)(r0 + r) * 128 + tid] = acc0[r];
    XR2[(size_t)(r0 + r) * 128 + tid] = acc1[r];
  }
}

// ---------------- GAT layer 2 fused (1 head) + BN/ELU + residual ----------------
__global__ __launch_bounds__(256)
void gat2_kernel(const float* __restrict__ XL, const float* __restrict__ XR,
                 const int* __restrict__ srcD, const int* __restrict__ eidx,
                 const int* __restrict__ offs, const float* __restrict__ a2,
                 const float* __restrict__ ABF, const float* __restrict__ XP,
                 float* __restrict__ Hout)
{
  const int lane = threadIdx.x & 63;
  const int wv = threadIdx.x >> 6;
  const int n = blockIdx.x * 4 + wv;
  const int b = blockIdx.y;
  __shared__ float lsh[4][96];
  const int beg = offs[n];
  const int deg = offs[n + 1] - beg;
  const float2 av = reinterpret_cast<const float2*>(a2)[lane];
  const float2 xr2 = reinterpret_cast<const float2*>(XR + (size_t)(b * 1000 + n) * 128)[lane];
  float m = -INFINITY, ssum = 0.f;
  for (int i = 0; i < deg; ++i) {
    const int e = eidx[beg + i];
    const int s = srcD[e];
    const float2 xl2 = reinterpret_cast<const float2*>(XL + (size_t)(b * 1000 + s) * 128)[lane];
    float p = lrelu(xl2.x + xr2.x) * av.x + lrelu(xl2.y + xr2.y) * av.y;
    p = rsum64(p);
    if (i < 96 && lane == 0) lsh[wv][i] = p;
    float mn = fmaxf(m, p);
    ssum = ssum * __expf(m - mn) + __expf(p - mn);
    m = mn;
  }
  const float inv = 1.f / ssum;
  __builtin_amdgcn_wave_barrier();
  float2 acc = make_float2(0.f, 0.f);
  for (int i = 0; i < deg; ++i) {
    const int e = eidx[beg + i];
    const int s = srcD[e];
    const float2 xl2 = reinterpret_cast<const float2*>(XL + (size_t)(b * 1000 + s) * 128)[lane];
    float lg;
    if (i < 96) lg = lsh[wv][i];
    else {
      float p = lrelu(xl2.x + xr2.x) * av.x + lrelu(xl2.y + xr2.y) * av.y;
      lg = rsum64(p);
    }
    const float al = __expf(lg - m) * inv;
    acc.x = fmaf(al, xl2.x, acc.x);
    acc.y = fmaf(al, xl2.y, acc.y);
  }
  const float2 A2 = reinterpret_cast<const float2*>(ABF + 512)[lane];
  const float2 B2 = reinterpret_cast<const float2*>(ABF + 640)[lane];
  const float2 xp = reinterpret_cast<const float2*>(XP + (size_t)(b * 1000 + n) * 128)[lane];
  float2 o;
  o.x = eluf(fmaf(acc.x, A2.x, B2.x)) + xp.x;
  o.y = eluf(fmaf(acc.y, A2.y, B2.y)) + xp.y;
  reinterpret_cast<float2*>(Hout + (size_t)(b * 1000 + n) * 128)[lane] = o;
}

// ---------------- fused 2-layer LSTM ----------------
#define FMA4(A, W, S) { (A).x = fmaf((W).x, (S), (A).x); (A).y = fmaf((W).y, (S), (A).y); \
                        (A).z = fmaf((W).z, (S), (A).z); (A).w = fmaf((W).w, (S), (A).w); }

__device__ __forceinline__ void lstm_gates(const float4* __restrict__ wp,
                                           const float (*xsh)[20], const float (*hsh)[20],
                                           int s0, float4 b,
                                           float4& g0, float4& g1, float4& g2, float4& g3)
{
  g0 = b; g1 = b; g2 = b; g3 = b;
  #pragma unroll 2
  for (int k = 0; k < 128; ++k) {
    float4 wih = wp[0], whh = wp[1];
    wp += 256;
    float4 xv = *reinterpret_cast<const float4*>(&xsh[k][s0]);
    float4 hv = *reinterpret_cast<const float4*>(&hsh[k][s0]);
    FMA4(g0, wih, xv.x); FMA4(g1, wih, xv.y); FMA4(g2, wih, xv.z); FMA4(g3, wih, xv.w);
    FMA4(g0, whh, hv.x); FMA4(g1, whh, hv.y); FMA4(g2, whh, hv.z); FMA4(g3, whh, hv.w);
  }
}
__device__ __forceinline__ float lstm_cell(float4 g, float& c) {
  const float ig = 1.f / (1.f + __expf(-g.x));
  const float fg = 1.f / (1.f + __expf(-g.y));
  const float gg = tanhf(g.z);
  const float og = 1.f / (1.f + __expf(-g.w));
  c = fmaf(fg, c, ig * gg);
  return og * tanhf(c);
}

__global__ __launch_bounds__(512, 1)
void lstm_kernel(const float* __restrict__ Hin, const float* __restrict__ LW,
                 const float* __restrict__ BC, float* __restrict__ LO)
{
  __shared__ float x_sh[128][20];
  __shared__ float h1_sh[128][20];
  __shared__ float h2_sh[128][20];
  const int tid = threadIdx.x;
  const int j = tid & 127;
  const int s0 = (tid >> 7) << 2;
  const int q0 = blockIdx.x << 4;
  for (int i = tid; i < 128 * 20; i += 512) {
    (&h1_sh[0][0])[i] = 0.f;
    (&h2_sh[0][0])[i] = 0.f;
  }
  const float4 b1 = *reinterpret_cast<const float4*>(BC + (j << 2));
  const float4 b2 = *reinterpret_cast<const float4*>(BC + 512 + (j << 2));
  const float4* LW4 = reinterpret_cast<const float4*>(LW);
  const float4* wp1 = LW4 + (j << 1);
  const float4* wp2 = LW4 + 32768 + (j << 1);
  float c1[4] = {0.f, 0.f, 0.f, 0.f}, c2[4] = {0.f, 0.f, 0.f, 0.f};
  __syncthreads();
  for (int t = 0; t < 16; ++t) {
    #pragma unroll
    for (int c = 0; c < 4; ++c) {
      int el = (c << 9) + tid;
      int s = el >> 7, k = el & 127;
      x_sh[k][s] = Hin[(size_t)((((q0 + s) << 4) + t)) * 128 + k];
    }
    __syncthreads();                                   // (A)
    float4 g0, g1, g2, g3;
    lstm_gates(wp1, x_sh, h1_sh, s0, b1, g0, g1, g2, g3);
    float h1v0 = lstm_cell(g0, c1[0]);
    float h1v1 = lstm_cell(g1, c1[1]);
    float h1v2 = lstm_cell(g2, c1[2]);
    float h1v3 = lstm_cell(g3, c1[3]);
    __syncthreads();                                   // (B)
    *reinterpret_cast<float4*>(&h1_sh[j][s0]) = make_float4(h1v0, h1v1, h1v2, h1v3);
    __syncthreads();                                   // (C)
    lstm_gates(wp2, h1_sh, h2_sh, s0, b2, g0, g1, g2, g3);
    float h2v0 = lstm_cell(g0, c2[0]);
    float h2v1 = lstm_cell(g1, c2[1]);
    float h2v2 = lstm_cell(g2, c2[2]);
    float h2v3 = lstm_cell(g3, c2[3]);
    __syncthreads();                                   // (D)
    *reinterpret_cast<float4*>(&h2_sh[j][s0]) = make_float4(h2v0, h2v1, h2v2, h2v3);
    LO[(size_t)((((q0 + s0 + 0) << 4) + t)) * 128 + j] = h2v0;
    LO[(size_t)((((q0 + s0 + 1) << 4) + t)) * 128 + j] = h2v1;
    LO[(size_t)((((q0 + s0 + 2) << 4) + t)) * 128 + j] = h2v2;
    LO[(size_t)((((q0 + s0 + 3) << 4) + t)) * 128 + j] = h2v3;
  }
}

// ---------------- attention pool + skip MLP + head ----------------
__global__ __launch_bounds__(64)
void attn_kernel(const float* __restrict__ LO, const float* __restrict__ X,
                 const float* __restrict__ Wa, const float* __restrict__ ba,
                 const float* __restrict__ bs1, const float* __restrict__ bs2,
                 const float* __restrict__ bh1, const float* __restrict__ bh2,
                 const float* __restrict__ Wh2, const float* __restrict__ HWT,
                 float* __restrict__ out)
{
  const int q = blockIdx.x, l = threadIdx.x;
  const float* lob = LO + (size_t)q * 2048;
  float loa[16], lobv[16];
  #pragma unroll
  for (int t = 0; t < 16; ++t) {
    loa[t]  = lob[t * 128 + l];
    lobv[t] = lob[t * 128 + 64 + l];
  }
  const float wa = Wa[l], wb = Wa[64 + l];
  float sc[16];
  #pragma unroll
  for (int t = 0; t < 16; ++t) sc[t] = rsum64(loa[t] * wa + lobv[t] * wb) + ba[0];
  float mx = sc[0];
  #pragma unroll
  for (int t = 1; t < 16; ++t) mx = fmaxf(mx, sc[t]);
  float den = 0.f;
  #pragma unroll
  for (int t = 0; t < 16; ++t) { sc[t] = __expf(sc[t] - mx); den += sc[t]; }
  const float inv = 1.f / den;
  float ca = 0.f, cb = 0.f;
  #pragma unroll
  for (int t = 0; t < 16; ++t) {
    float w = sc[t] * inv;
    ca = fmaf(w, loa[t], ca);
    cb = fmaf(w, lobv[t], cb);
  }
  __shared__ float zsh[160];
  __shared__ float hsk[64];
  __shared__ float skin[16];
  zsh[l] = ca; zsh[64 + l] = cb;
  const int bb = q / 1000, nn = q - bb * 1000;
  if (l < 13) skin[l] = X[(size_t)((bb * 16 + 15) * 1000 + nn) * 32 + l];
  __syncthreads();
  float h1 = bs1[l];
  for (int c = 0; c < 13; ++c) h1 = fmaf(skin[c], HWT[c * 64 + l], h1);
  h1 = geluf(h1);
  hsk[l] = h1;
  __syncthreads();
  if (l < 32) {
    float a = bs2[l];
    for (int jj = 0; jj < 64; ++jj) a = fmaf(hsk[jj], HWT[832 + jj * 32 + l], a);
    zsh[128 + l] = a;
  }
  __syncthreads();
  float hh = bh1[l];
  for (int r = 0; r < 160; ++r) hh = fmaf(zsh[r], HWT[2880 + r * 64 + l], hh);
  hh = geluf(hh);
  float s = rsum64(hh * Wh2[l]);
  if (l == 0) out[q] = s + bh2[0];
}

// ---------------- launch ----------------
extern "C" void kernel_launch(void* const* d_in, const int* in_sizes, int n_in,
                              void* d_out, int out_size, void* d_ws, size_t ws_size,
                              hipStream_t stream)
{
  const float* x    = (const float*)d_in[0];
  const int*   ei   = (const int*)d_in[1];
  const float* Wp   = (const float*)d_in[2];
  const float* bp   = (const float*)d_in[3];
  const float* Wl1  = (const float*)d_in[4];
  const float* Wr1  = (const float*)d_in[5];
  const float* a1   = (const float*)d_in[6];
  const float* bg1  = (const float*)d_in[7];
  const float* g1   = (const float*)d_in[8];
  const float* be1  = (const float*)d_in[9];
  const float* m1   = (const float*)d_in[10];
  const float* v1   = (const float*)d_in[11];
  const float* Wl2  = (const float*)d_in[12];
  const float* Wr2  = (const float*)d_in[13];
  const float* a2   = (const float*)d_in[14];
  const float* bg2  = (const float*)d_in[15];
  const float* g2   = (const float*)d_in[16];
  const float* be2  = (const float*)d_in[17];
  const float* m2   = (const float*)d_in[18];
  const float* v2   = (const float*)d_in[19];
  const float* Wih0 = (const float*)d_in[20];
  const float* Whh0 = (const float*)d_in[21];
  const float* bih0 = (const float*)d_in[22];
  const float* bhh0 = (const float*)d_in[23];
  const float* Wih1 = (const float*)d_in[24];
  const float* Whh1 = (const float*)d_in[25];
  const float* bih1 = (const float*)d_in[26];
  const float* bhh1 = (const float*)d_in[27];
  const float* Wa   = (const float*)d_in[28];
  const float* ba   = (const float*)d_in[29];
  const float* Ws1  = (const float*)d_in[30];
  const float* bs1  = (const float*)d_in[31];
  const float* Ws2  = (const float*)d_in[32];
  const float* bs2  = (const float*)d_in[33];
  const float* Wh1  = (const float*)d_in[34];
  const float* bh1  = (const float*)d_in[35];
  const float* Wh2  = (const float*)d_in[36];
  const float* bh2  = (const float*)d_in[37];

  float* ws = (float*)d_ws;
  int* srcD   = (int*)(ws + O_SRCD);
  int* dstD   = (int*)(ws + O_DSTD);
  int* counts = (int*)(ws + O_COUNTS);
  int* offs   = (int*)(ws + O_OFFS);
  int* curs   = (int*)(ws + O_CURS);
  int* eidx   = (int*)(ws + O_EIDX);
  float* PW1  = ws + O_PW1;
  float* PW2  = ws + O_PW2;
  float* LW   = ws + O_LW;
  float* BC   = ws + O_BCOMB;
  float* ABF  = ws + O_ABF;
  float* HWT  = ws + O_HWT;
  float* XL1  = ws + O_BIG0;
  float* XR1  = ws + O_BIG1;
  float* H1   = ws + O_BIG2;
  float* XP   = ws + O_BIG3;
  float* Hres = ws + O_BIG4;
  float* XL2  = ws + O_BIG0;             // reuse (XL1 dead)
  float* XR2  = ws + O_BIG0 + 8192000u;
  float* LOp  = ws + O_BIG1;             // reuse (XR1 dead)
  float* outp = (float*)d_out;

  prep_edges<<<67, 256, 0, stream>>>(ei, srcD, dstD, counts);
  hist_kernel<<<67, 256, 0, stream>>>(dstD, counts);
  scan_kernel<<<1, 1024, 0, stream>>>(counts, offs, curs);
  fill_kernel<<<67, 256, 0, stream>>>(dstD, curs, eidx);
  pack_kernel<<<1024, 256, 0, stream>>>(Wl1, Wr1, Wp, Wl2, Wr2,
      Wih0, Whh0, bih0, bhh0, Wih1, Whh1, bih1, bhh1,
      g1, be1, m1, v1, bg1, g2, be2, m2, v2, bg2,
      Ws1, Ws2, Wh1, PW1, PW2, LW, BC, ABF, HWT);
  proj1_kernel<<<4000, 320, 0, stream>>>(x, PW1, bp, XL1, XR1, XP);
  gat1_kernel<<<dim3(250, 64), 256, 0, stream>>>(XL1, XR1, srcD, eidx, offs, a1, ABF, H1);
  proj2_kernel<<<2000, 128, 0, stream>>>(H1, PW2, XL2, XR2);
  gat2_kernel<<<dim3(250, 64), 256, 0, stream>>>(XL2, XR2, srcD, eidx, offs, a2, ABF, XP, Hres);
  lstm_kernel<<<250, 512, 0, stream>>>(Hres, LW, BC, LOp);
  attn_kernel<<<4000, 64, 0, stream>>>(LOp, x, Wa, ba, bs1, bs2, bh1, bh2, Wh2, HWT, outp);
}